// Round 5
// baseline (819.367 us; speedup 1.0000x reference)
//
#include <hip/hip_runtime.h>
#include <hip/hip_bf16.h>

typedef unsigned long long u64;

#define B_IMG 16
#define N_ANC 25200
#define NCLS 80
#define ROW_F 85           // 5 + 80 floats per anchor
#define CONF_T 0.25f
#define IOU_T 0.45f
#define MAX_DET 1000
#define K_NMS 2048
#define MAX_WH 7680.0f
#define CAND_CAP 4096      // per-image cap (expected ~1070 valid; >90 sigma margin)
#define RANK_SLICES 4

// ---------------- workspace layout (bytes) ----------------
// [0,64)      : int count[16]   (obj-gate counts)
// [128,192)   : int nkeys[16]   (valid-key counts)
// [256,320)   : int ncand[16]   (ranked slots, set by rank_kernel)
// [1K,257K)   : int candn[16][4096]      (gated anchor indices)
// [512K,1M)   : u64 keys[16][4096]       (dense sortable keys)
// [1M,1.5M)   : float4 boxes[16][2048]   (slots >= ncand never read)
// [1.5M,+128K): float area[16][2048]
// [1.625M,+128K): int candidx[16][2048]
// [2M,10M)    : u64 supmat[16][2048][32] (row i: words [i>>6, ceil(M/64)) written)

// Kernel 1: obj-only gate + per-image compaction of anchor indices.
// Memory-bound: one 4B load per anchor (stride 340B -> 64B-line floor ~26 MB).
__global__ __launch_bounds__(256) void gate_kernel(const float* __restrict__ pred,
                                                   int* __restrict__ count,
                                                   int* __restrict__ candn) {
    int gid = blockIdx.x * 256 + threadIdx.x;      // exactly B*N threads
    int b = gid / N_ANC;
    int n = gid - b * N_ANC;
    float obj = pred[(size_t)gid * ROW_F + 4];
    if (!(obj > CONF_T)) return;                   // ~95.8% exit; ~2.7 active lanes/wave
    int pos = atomicAdd(&count[b], 1);
    if (pos < CAND_CAP) candn[b * CAND_CAP + pos] = n;
}

// Kernel 2: dense class-max pass — one compacted anchor per lane, all lanes do real work.
// Emits sortable keys densely (second atomic counter tolerates best<=CONF dropouts).
// key = (monotone(best) << 22) | ((32767-n) << 7) | class
//   -> u64 descending == (score desc, anchor-index asc) == lax.top_k order. Keys distinct.
__global__ __launch_bounds__(256) void cls_kernel(const float* __restrict__ pred,
                                                  const int* __restrict__ count,
                                                  const int* __restrict__ candn,
                                                  int* __restrict__ nkeys,
                                                  u64* __restrict__ keys) {
    int item = blockIdx.x * 256 + threadIdx.x;     // B_IMG*CAND_CAP items; 16 blocks/image
    int b = item >> 12;                            // block-uniform (256 | 4096)
    int t = item & (CAND_CAP - 1);
    int cnt = min(count[b], CAND_CAP);
    if (t >= cnt) return;
    int n = candn[b * CAND_CAP + t];
    const float* row = pred + ((size_t)b * N_ANC + n) * ROW_F;
    float obj = row[4];
    float best = -1.0f; int bj = 0;
    #pragma unroll 8
    for (int c = 0; c < NCLS; ++c) {
        float s = __fmul_rn(row[5 + c], obj);      // exact repl of cls*obj
        if (s > best) { best = s; bj = c; }        // strict > == first-max (matches argmax)
    }
    if (!(best > CONF_T)) return;                  // rare (P~1e-6) but must match reference
    unsigned ord = __float_as_uint(best) ^ 0x80000000u;  // best>0 -> monotone map
    u64 key = ((u64)ord << 22) | ((u64)(32767 - n) << 7) | (u64)bj;
    int pos = atomicAdd(&nkeys[b], 1);
    if (pos < CAND_CAP) keys[(size_t)b * CAND_CAP + pos] = key;
}

// Kernel 3: O(M^2) rank-sort, 4 slice-blocks per image (ranks injective -> disjoint writes).
// rank(t) = #{j: key[j] > key[t]} reproduces top_k order exactly; rank >= 2048 dropped.
__global__ __launch_bounds__(1024) void rank_kernel(const u64* __restrict__ keys,
                                                    const int* __restrict__ nkeys,
                                                    int* __restrict__ ncand,
                                                    const float* __restrict__ pred,
                                                    float4* __restrict__ boxes,
                                                    float* __restrict__ area,
                                                    int* __restrict__ candidx) {
    __shared__ u64 s_keys[CAND_CAP];               // 32 KB
    int b = blockIdx.x;
    int s = blockIdx.y;
    int M = min(nkeys[b], CAND_CAP);
    if (s == 0 && threadIdx.x == 0) ncand[b] = min(M, K_NMS);
    int t0 = s * 1024;
    if (t0 >= M) return;                           // block-uniform exit
    for (int t = threadIdx.x; t < M; t += 1024)
        s_keys[t] = keys[(size_t)b * CAND_CAP + t];
    __syncthreads();
    int t = t0 + threadIdx.x;
    if (t >= M) return;
    u64 key = s_keys[t];
    int rank = 0;
    for (int j = 0; j < M; ++j)                    // wave-uniform LDS broadcast
        rank += (s_keys[j] > key) ? 1 : 0;
    if (rank < K_NMS) {
        int cls = (int)(key & 127ULL);
        int n = 32767 - (int)((key >> 7) & 32767ULL);
        const float* row = pred + ((size_t)b * N_ANC + n) * ROW_F;
        float bx = row[0], by = row[1], bw = row[2], bh = row[3];
        float off = (float)cls * MAX_WH;                       // exact product
        float x1 = __fadd_rn(__fsub_rn(bx, __fmul_rn(bw, 0.5f)), off);
        float y1 = __fadd_rn(__fsub_rn(by, __fmul_rn(bh, 0.5f)), off);
        float x2 = __fadd_rn(__fadd_rn(bx, __fmul_rn(bw, 0.5f)), off);
        float y2 = __fadd_rn(__fadd_rn(by, __fmul_rn(bh, 0.5f)), off);
        size_t o = (size_t)b * K_NMS + rank;
        boxes[o] = make_float4(x1, y1, x2, y2);
        area[o] = __fmul_rn(__fsub_rn(x2, x1), __fsub_rn(y2, y1)); // from offset coords, like ref
        candidx[o] = n;
    }
}

// Kernel 4: suppression bit-matrix. Row i, word w in [i>>6, ceil(M/64)): bit j =
// (iou(i,j)>0.45 && j>i). Words >= ceil(M/64) left unwritten: masked by vmask in kernel 5.
__global__ __launch_bounds__(256) void iou_kernel(const float4* __restrict__ boxes,
                                                  const float* __restrict__ area,
                                                  const int* __restrict__ ncand,
                                                  u64* __restrict__ supmat) {
    __shared__ float4 s_box[K_NMS];                // 32 KB
    __shared__ float s_area[K_NMS];                // 8 KB
    int b = blockIdx.y;
    int M = ncand[b];
    int r0 = blockIdx.x * 32;
    if (r0 >= M) return;
    for (int t = threadIdx.x; t < K_NMS; t += 256) {
        if (t < M) {
            s_box[t] = boxes[(size_t)b * K_NMS + t];
            s_area[t] = area[(size_t)b * K_NMS + t];
        } else {                                   // synthesized inert filler (never stored)
            s_box[t] = make_float4(0.f, 0.f, 0.f, 0.f);
            s_area[t] = 0.f;
        }
    }
    __syncthreads();
    int wave = threadIdx.x >> 6, lane = threadIdx.x & 63;
    int wend = (M + 63) >> 6;                      // columns >= wend*64 are inert
    for (int rr = 0; rr < 8; ++rr) {
        int i = r0 + wave * 8 + rr;                // wave-uniform
        if (i >= M) continue;
        float4 bi = s_box[i]; float ai = s_area[i];
        int wstart = i >> 6;
        u64* outrow = supmat + ((size_t)b * K_NMS + i) * 32;
        if (lane < wstart) outrow[lane] = 0ULL;    // low words read by kernel 5 accumulation
        for (int w = wstart; w < wend; ++w) {
            int j = w * 64 + lane;
            float4 bj = s_box[j]; float aj = s_area[j];
            float iw = fmaxf(__fsub_rn(fminf(bi.z, bj.z), fmaxf(bi.x, bj.x)), 0.0f);
            float ih = fmaxf(__fsub_rn(fminf(bi.w, bj.w), fmaxf(bi.y, bj.y)), 0.0f);
            float inter = __fmul_rn(iw, ih);
            float uni = __fsub_rn(__fadd_rn(ai, aj), inter);
            float iou = (uni > 0.0f) ? __fdiv_rn(inter, uni) : 0.0f;  // exact repl of ref
            bool bit = (j > i) && (iou > IOU_T);
            u64 mask = __ballot(bit);
            if (lane == 0) outrow[w] = mask;
        }
    }
}

// Kernel 5: sequential greedy suppression (1 wave/image, double-buffered staging)
// + rank<1000 + 80-wide sums.
__global__ __launch_bounds__(256) void nms_kernel(const u64* __restrict__ supmat,
                                                  const int* __restrict__ ncand,
                                                  const int* __restrict__ candidx,
                                                  const float* __restrict__ pred,
                                                  float* __restrict__ out) {
    __shared__ u64 s_rows[2][64 * 32];             // 2 x 16 KB double buffer
    __shared__ int s_klist[MAX_DET];
    __shared__ double s_part[2][NCLS];
    __shared__ int s_K;
    int b = blockIdx.x;
    int M = ncand[b];
    int tid = threadIdx.x;
    int lane = tid & 63, wave = tid >> 6;
    unsigned remv_lo = 0u, remv_hi = 0u;           // lane w (<32) holds u64 word w of removal mask
    const u64* base = supmat + (size_t)b * K_NMS * 32;
    int nchunks = (M + 63) >> 6;
    for (int t = tid; t < 2048 && nchunks > 0; t += 256)
        s_rows[0][t] = base[t];                    // prologue: stage chunk 0
    __syncthreads();
    for (int c = 0; c < nchunks; ++c) {
        int buf = c & 1;
        if (wave != 0) {                           // waves 1-3: prefetch chunk c+1
            int cn = c + 1;
            if (cn < nchunks) {
                size_t off = (size_t)cn * 2048;
                for (int t = tid - 64; t < 2048; t += 192)
                    s_rows[buf ^ 1][t] = base[off + t];
            }
        } else {                                   // wave 0: serial greedy scan of chunk c
            int c0 = c * 64;
            int lim = min(64, M - c0);
            for (int ii = 0; ii < lim; ++ii) {
                int i = c0 + ii;
                unsigned half = ((i >> 5) & 1) ? remv_hi : remv_lo;
                unsigned wv = __builtin_amdgcn_readlane(half, i >> 6);
                bool kept = ((wv >> (i & 31)) & 1u) == 0u;   // uniform across wave
                u64 rowm = (lane < 32) ? s_rows[buf][ii * 32 + lane] : 0ULL;
                if (kept) {
                    remv_lo |= (unsigned)rowm;
                    remv_hi |= (unsigned)(rowm >> 32);
                }
            }
        }
        __syncthreads();
    }
    if (wave == 0) {
        int w = lane;
        u64 keepw = 0ULL;
        if (w < 32) {
            int lo = w * 64;
            u64 vmask = (M >= lo + 64) ? ~0ULL : (M <= lo ? 0ULL : ((1ULL << (M - lo)) - 1ULL));
            u64 remv = ((u64)remv_hi << 32) | remv_lo;
            keepw = (~remv) & vmask;               // vmask kills garbage words >= ceil(M/64)
        }
        int c = __popcll(keepw);
        int sc = c;
        for (int o = 1; o < 64; o <<= 1) { int v = __shfl_up(sc, o); if (lane >= o) sc += v; }
        int excl = sc - c;
        int Ktot = __shfl(sc, 63);
        int K = min(Ktot, MAX_DET);
        if (lane == 0) s_K = K;
        u64 m = keepw; int r = excl;
        while (m) {
            int bit = __ffsll(m) - 1; m &= m - 1;
            if (r < K) s_klist[r] = candidx[(size_t)b * K_NMS + w * 64 + bit];
            r++;
        }
    }
    __syncthreads();
    int K = s_K;
    // 3 groups of 80 threads sum k-strides; coalesced 80-float row reads per group.
    int g = tid / NCLS;                            // 0,1,2 active; tid>=240 idle
    int c = tid - g * NCLS;
    double acc = 0.0;
    if (g < 3) {
        for (int k = g; k < K; k += 3) {
            int n = s_klist[k];
            const float* row = pred + ((size_t)b * N_ANC + n) * ROW_F;
            acc += (double)__fmul_rn(row[5 + c], row[4]);
        }
        if (g > 0) s_part[g - 1][c] = acc;
    }
    __syncthreads();
    if (tid < NCLS)
        out[b * NCLS + tid] = (float)(acc + s_part[0][tid] + s_part[1][tid]);
}

extern "C" void kernel_launch(void* const* d_in, const int* in_sizes, int n_in,
                              void* d_out, int out_size, void* d_ws, size_t ws_size,
                              hipStream_t stream) {
    const float* pred = (const float*)d_in[0];
    float* out = (float*)d_out;
    char* w = (char*)d_ws;
    int* count    = (int*)(w + 0);
    int* nkeys    = (int*)(w + 128);
    int* ncand    = (int*)(w + 256);
    int* candn    = (int*)(w + 1024);
    u64* keys     = (u64*)(w + 524288);
    float4* boxes = (float4*)(w + (1u << 20));
    float* area   = (float*)(w + (1u << 20) + 524288);
    int* candidx  = (int*)(w + (1u << 20) + 524288 + 131072);
    u64* supmat   = (u64*)(w + (2u << 20));

    hipMemsetAsync(w, 0, 512, stream);             // count + nkeys + ncand
    gate_kernel<<<(B_IMG * N_ANC) / 256, 256, 0, stream>>>(pred, count, candn);
    cls_kernel<<<(B_IMG * CAND_CAP) / 256, 256, 0, stream>>>(pred, count, candn, nkeys, keys);
    rank_kernel<<<dim3(B_IMG, RANK_SLICES), 1024, 0, stream>>>(keys, nkeys, ncand, pred, boxes, area, candidx);
    iou_kernel<<<dim3(64, B_IMG), 256, 0, stream>>>(boxes, area, ncand, supmat);
    nms_kernel<<<B_IMG, 256, 0, stream>>>(supmat, ncand, candidx, pred, out);
}

// Round 7
// 549.560 us; speedup vs baseline: 1.4910x; 1.4910x over previous
//
#include <hip/hip_runtime.h>

typedef unsigned long long u64;

#define B_IMG 16
#define N_ANC 25200
#define NCLS 80
#define ROW_F 85           // 5 + 80 floats per anchor
#define CONF_T 0.25f
#define IOU_T 0.45f
#define MAX_DET 1000
#define K_NMS 2048
#define MAX_WH 7680.0f
#define CAND_CAP 2048      // per-image cap (mean ~1065 valid, sigma ~32 -> +30 sigma)
#define TILE_A 128         // anchors per scan tile
#define TILE_F (TILE_A * ROW_F)   // 10880 floats = 42.5 KB
#define RANK_SLICES 2

// ---------------- workspace layout (bytes, total ~9.97 MB) ----------------
#define OFF_COUNT 0            // int count[16]
#define OFF_NCAND 256          // int ncand[16]
#define OFF_KEYS  4096         // u64 keys[16][2048]      (256 KB)
#define OFF_KBOX  266240       // float4 kbox[16][2048]   (512 KB)
#define OFF_BOXES 790528       // float4 boxes[16][2048]  (512 KB)
#define OFF_AREA  1314816      // float area[16][2048]    (128 KB)
#define OFF_CIDX  1445888      // int candidx[16][2048]   (128 KB)
#define OFF_SUP   1576960      // u64 supmat[16][2048][32] (8 MB)

// Kernel 1: fused coalesced scan. Stages 128 full rows (42.5 KB) into LDS via
// float4 loads (every wave-instruction contiguous), then one thread per anchor
// gates + class-maxes FROM LDS. Emits sortable key + raw box per candidate.
// key = (monotone(best) << 22) | ((32767-n) << 7) | class
//   -> u64 descending == (score desc, anchor-index asc) == lax.top_k order. Keys distinct.
__global__ __launch_bounds__(256) void scan_kernel(const float* __restrict__ pred,
                                                   int* __restrict__ count,
                                                   u64* __restrict__ keys,
                                                   float4* __restrict__ kbox) {
    __shared__ float s[TILE_F];
    int blk = blockIdx.x;                          // 3150 tiles, exact cover
    const float4* src = (const float4*)(pred + (size_t)blk * TILE_F);
    float4* dst = (float4*)s;
    for (int i = threadIdx.x; i < TILE_F / 4; i += 256)
        dst[i] = src[i];                           // fully coalesced HBM read
    __syncthreads();
    int t = threadIdx.x;
    if (t >= TILE_A) return;                       // waves 2,3 load-only
    int gid = blk * TILE_A + t;
    int b = gid / N_ANC;                           // tiles may straddle images: per-anchor b
    int n = gid - b * N_ANC;
    const float* row = s + t * ROW_F;              // LDS stride 85: <=2 lanes/bank, free
    float obj = row[4];
    if (!(obj > CONF_T)) return;                   // ~95.8% exit
    float best = -1.0f; int bj = 0;
    #pragma unroll 8
    for (int c = 0; c < NCLS; ++c) {
        float sc = __fmul_rn(row[5 + c], obj);     // exact repl of cls*obj
        if (sc > best) { best = sc; bj = c; }      // strict > == first-max (matches argmax)
    }
    if (!(best > CONF_T)) return;                  // rare but must match reference
    unsigned ord = __float_as_uint(best) ^ 0x80000000u;  // best>0 -> monotone map
    u64 key = ((u64)ord << 22) | ((u64)(32767 - n) << 7) | (u64)bj;
    int pos = atomicAdd(&count[b], 1);
    if (pos < CAND_CAP) {
        keys[b * CAND_CAP + pos] = key;
        kbox[b * CAND_CAP + pos] = make_float4(row[0], row[1], row[2], row[3]);
    }
}

// Kernel 2: O(M^2) rank-sort, 2 slice-blocks/image (ranks injective -> disjoint writes).
// rank(t) = #{j: key[j] > key[t]} reproduces top_k order exactly. M <= 2048 == K_NMS,
// so every rank lands. Box read is slot-indexed kbox: coalesced, no pred gather.
__global__ __launch_bounds__(1024) void rank_kernel(const u64* __restrict__ keys,
                                                    const int* __restrict__ count,
                                                    int* __restrict__ ncand,
                                                    const float4* __restrict__ kbox,
                                                    float4* __restrict__ boxes,
                                                    float* __restrict__ area,
                                                    int* __restrict__ candidx) {
    __shared__ u64 s_keys[CAND_CAP];               // 16 KB
    int b = blockIdx.x, sl = blockIdx.y;
    int M = min(count[b], CAND_CAP);
    if (sl == 0 && threadIdx.x == 0) ncand[b] = M;
    int t0 = sl * 1024;
    if (t0 >= M) return;                           // block-uniform exit
    for (int t = threadIdx.x; t < M; t += 1024)
        s_keys[t] = keys[b * CAND_CAP + t];
    __syncthreads();
    int t = t0 + threadIdx.x;
    if (t >= M) return;
    u64 key = s_keys[t];
    int rank = 0;
    for (int j = 0; j < M; ++j)                    // wave-uniform LDS broadcast
        rank += (s_keys[j] > key) ? 1 : 0;
    float4 b4 = kbox[b * CAND_CAP + t];            // coalesced by t
    int cls = (int)(key & 127ULL);
    int n = 32767 - (int)((key >> 7) & 32767ULL);
    float off = (float)cls * MAX_WH;                           // exact product
    float x1 = __fadd_rn(__fsub_rn(b4.x, __fmul_rn(b4.z, 0.5f)), off);
    float y1 = __fadd_rn(__fsub_rn(b4.y, __fmul_rn(b4.w, 0.5f)), off);
    float x2 = __fadd_rn(__fadd_rn(b4.x, __fmul_rn(b4.z, 0.5f)), off);
    float y2 = __fadd_rn(__fadd_rn(b4.y, __fmul_rn(b4.w, 0.5f)), off);
    size_t o = (size_t)b * K_NMS + rank;
    boxes[o] = make_float4(x1, y1, x2, y2);
    area[o] = __fmul_rn(__fsub_rn(x2, x1), __fsub_rn(y2, y1));  // from offset coords, like ref
    candidx[o] = n;
}

// Kernel 3: suppression bit-matrix. Row i, word w in [i>>6, ceil(M/64)): bit j =
// (iou(i,j)>0.45 && j>i). Words >= ceil(M/64) unwritten: masked by vmask in kernel 4.
__global__ __launch_bounds__(256) void iou_kernel(const float4* __restrict__ boxes,
                                                  const float* __restrict__ area,
                                                  const int* __restrict__ ncand,
                                                  u64* __restrict__ supmat) {
    __shared__ float4 s_box[K_NMS];                // 32 KB
    __shared__ float s_area[K_NMS];                // 8 KB
    int b = blockIdx.y;
    int M = ncand[b];
    int r0 = blockIdx.x * 32;
    if (r0 >= M) return;
    for (int t = threadIdx.x; t < K_NMS; t += 256) {
        if (t < M) {
            s_box[t] = boxes[(size_t)b * K_NMS + t];
            s_area[t] = area[(size_t)b * K_NMS + t];
        } else {                                   // synthesized inert filler (never stored)
            s_box[t] = make_float4(0.f, 0.f, 0.f, 0.f);
            s_area[t] = 0.f;
        }
    }
    __syncthreads();
    int wave = threadIdx.x >> 6, lane = threadIdx.x & 63;
    int wend = (M + 63) >> 6;                      // columns >= wend*64 are inert
    for (int rr = 0; rr < 8; ++rr) {
        int i = r0 + wave * 8 + rr;                // wave-uniform
        if (i >= M) continue;
        float4 bi = s_box[i]; float ai = s_area[i];
        int wstart = i >> 6;
        u64* outrow = supmat + ((size_t)b * K_NMS + i) * 32;
        if (lane < wstart) outrow[lane] = 0ULL;    // low words read by kernel 4 accumulation
        for (int w = wstart; w < wend; ++w) {
            int j = w * 64 + lane;
            float4 bj = s_box[j]; float aj = s_area[j];
            float iw = fmaxf(__fsub_rn(fminf(bi.z, bj.z), fmaxf(bi.x, bj.x)), 0.0f);
            float ih = fmaxf(__fsub_rn(fminf(bi.w, bj.w), fmaxf(bi.y, bj.y)), 0.0f);
            float inter = __fmul_rn(iw, ih);
            float uni = __fsub_rn(__fadd_rn(ai, aj), inter);
            float iou = (uni > 0.0f) ? __fdiv_rn(inter, uni) : 0.0f;  // exact repl of ref
            bool bit = (j > i) && (iou > IOU_T);
            u64 mask = __ballot(bit);
            if (lane == 0) outrow[w] = mask;
        }
    }
}

// Kernel 4: sequential greedy suppression (1 wave/image, double-buffered staging)
// + rank<1000 + 80-wide sums with per-row coalesced reads.
__global__ __launch_bounds__(256) void nms_kernel(const u64* __restrict__ supmat,
                                                  const int* __restrict__ ncand,
                                                  const int* __restrict__ candidx,
                                                  const float* __restrict__ pred,
                                                  float* __restrict__ out) {
    __shared__ u64 s_rows[2][64 * 32];             // 2 x 16 KB double buffer
    __shared__ int s_klist[MAX_DET];
    __shared__ double s_part[2][NCLS];
    __shared__ int s_K;
    int b = blockIdx.x;
    int M = ncand[b];
    int tid = threadIdx.x;
    int lane = tid & 63, wave = tid >> 6;
    unsigned remv_lo = 0u, remv_hi = 0u;           // lane w (<32) holds u64 word w of removal mask
    const u64* base = supmat + (size_t)b * K_NMS * 32;
    int nchunks = (M + 63) >> 6;
    for (int t = tid; t < 2048 && nchunks > 0; t += 256)
        s_rows[0][t] = base[t];                    // prologue: stage chunk 0
    __syncthreads();
    for (int c = 0; c < nchunks; ++c) {
        int buf = c & 1;
        if (wave != 0) {                           // waves 1-3: prefetch chunk c+1
            int cn = c + 1;
            if (cn < nchunks) {
                size_t off = (size_t)cn * 2048;
                for (int t = tid - 64; t < 2048; t += 192)
                    s_rows[buf ^ 1][t] = base[off + t];
            }
        } else {                                   // wave 0: serial greedy scan of chunk c
            int c0 = c * 64;
            int lim = min(64, M - c0);
            for (int ii = 0; ii < lim; ++ii) {
                int i = c0 + ii;
                unsigned half = ((i >> 5) & 1) ? remv_hi : remv_lo;
                unsigned wv = __builtin_amdgcn_readlane(half, i >> 6);
                bool kept = ((wv >> (i & 31)) & 1u) == 0u;   // uniform across wave
                u64 rowm = (lane < 32) ? s_rows[buf][ii * 32 + lane] : 0ULL;
                if (kept) {
                    remv_lo |= (unsigned)rowm;
                    remv_hi |= (unsigned)(rowm >> 32);
                }
            }
        }
        __syncthreads();
    }
    if (wave == 0) {
        int w = lane;
        u64 keepw = 0ULL;
        if (w < 32) {
            int lo = w * 64;
            u64 vmask = (M >= lo + 64) ? ~0ULL : (M <= lo ? 0ULL : ((1ULL << (M - lo)) - 1ULL));
            u64 remv = ((u64)remv_hi << 32) | remv_lo;
            keepw = (~remv) & vmask;               // vmask kills garbage words >= ceil(M/64)
        }
        int c = __popcll(keepw);
        int sc = c;
        for (int o = 1; o < 64; o <<= 1) { int v = __shfl_up(sc, o); if (lane >= o) sc += v; }
        int excl = sc - c;
        int Ktot = __shfl(sc, 63);
        int K = min(Ktot, MAX_DET);
        if (lane == 0) s_K = K;
        u64 m = keepw; int r = excl;
        while (m) {
            int bit = __ffsll(m) - 1; m &= m - 1;
            if (r < K) s_klist[r] = candidx[(size_t)b * K_NMS + w * 64 + bit];
            r++;
        }
    }
    __syncthreads();
    int K = s_K;
    // 3 groups of 80 CONSECUTIVE threads; group reads ONE row segment (320 B,
    // 5-6 lines) per iteration — coalesced, vs 64 scattered lines before.
    int g = tid / NCLS;                            // 0,1,2 active; tid>=240 idle
    int c = tid - g * NCLS;
    double acc = 0.0;
    if (g < 3) {
        #pragma unroll 4
        for (int k = g; k < K; k += 3) {
            int n = s_klist[k];
            const float* row = pred + ((size_t)b * N_ANC + n) * ROW_F;
            acc += (double)__fmul_rn(row[5 + c], row[4]);
        }
        if (g > 0) s_part[g - 1][c] = acc;
    }
    __syncthreads();
    if (tid < NCLS)
        out[b * NCLS + tid] = (float)(acc + s_part[0][tid] + s_part[1][tid]);
}

extern "C" void kernel_launch(void* const* d_in, const int* in_sizes, int n_in,
                              void* d_out, int out_size, void* d_ws, size_t ws_size,
                              hipStream_t stream) {
    const float* pred = (const float*)d_in[0];
    float* out = (float*)d_out;
    char* w = (char*)d_ws;
    int* count    = (int*)(w + OFF_COUNT);
    int* ncand    = (int*)(w + OFF_NCAND);
    u64* keys     = (u64*)(w + OFF_KEYS);
    float4* kbox  = (float4*)(w + OFF_KBOX);
    float4* boxes = (float4*)(w + OFF_BOXES);
    float* area   = (float*)(w + OFF_AREA);
    int* candidx  = (int*)(w + OFF_CIDX);
    u64* supmat   = (u64*)(w + OFF_SUP);

    hipMemsetAsync(w, 0, 512, stream);             // count (+ncand)
    scan_kernel<<<(B_IMG * N_ANC) / TILE_A, 256, 0, stream>>>(pred, count, keys, kbox);
    rank_kernel<<<dim3(B_IMG, RANK_SLICES), 1024, 0, stream>>>(keys, count, ncand, kbox, boxes, area, candidx);
    iou_kernel<<<dim3(64, B_IMG), 256, 0, stream>>>(boxes, area, ncand, supmat);
    nms_kernel<<<B_IMG, 256, 0, stream>>>(supmat, ncand, candidx, pred, out);
}

// Round 8
// 391.099 us; speedup vs baseline: 2.0950x; 1.4052x over previous
//
#include <hip/hip_runtime.h>

typedef unsigned long long u64;

#define B_IMG 16
#define N_ANC 25200
#define NCLS 80
#define ROW_F 85           // 5 + 80 floats per anchor
#define CONF_T 0.25f
#define IOU_T 0.45f
#define MAX_DET 1000
#define K_NMS 2048
#define MAX_WH 7680.0f
#define CAND_CAP 2048      // per-image cap (mean ~1065 valid, sigma ~32 -> +30 sigma)
#define TILE_A 128         // anchors per scan tile
#define TILE_F (TILE_A * ROW_F)   // 10880 floats = 42.5 KB
#define RANK_SLICES 2

// ---------------- workspace layout (bytes, total ~9.97 MB) ----------------
#define OFF_COUNT 0            // int count[16*16]  (64-B stride per image: no line sharing)
#define OFF_NCAND 1024         // int ncand[16]
#define OFF_KEYS  4096         // u64 keys[16][2048]      (256 KB)
#define OFF_KBOX  266240       // float4 kbox[16][2048]   (512 KB)
#define OFF_BOXES 790528       // float4 boxes[16][2048]  (512 KB)
#define OFF_AREA  1314816      // float area[16][2048]    (128 KB)
#define OFF_CIDX  1445888      // int candidx[16][2048]   (128 KB)
#define OFF_SUP   1576960      // u64 supmat[16][2048][32] (8 MB)

// Kernel 1: fused coalesced scan. Stages 128 full rows (42.5 KB) into LDS via
// float4 loads, one thread per anchor gates + class-maxes FROM LDS.
// Compaction via WAVE-AGGREGATED atomics (1 atomic per wave per image-group,
// counters padded to 64 B) — R7 showed per-thread same-line atomics serialized
// the whole kernel at ~12 ns each.
// key = (monotone(best) << 22) | ((32767-n) << 7) | class
//   -> u64 descending == (score desc, anchor-index asc) == lax.top_k order. Keys distinct.
__global__ __launch_bounds__(256) void scan_kernel(const float* __restrict__ pred,
                                                   int* __restrict__ count,
                                                   u64* __restrict__ keys,
                                                   float4* __restrict__ kbox) {
    __shared__ float s[TILE_F];
    int blk = blockIdx.x;                          // 3150 tiles, exact cover
    const float4* src = (const float4*)(pred + (size_t)blk * TILE_F);
    float4* dst = (float4*)s;
    for (int i = threadIdx.x; i < TILE_F / 4; i += 256)
        dst[i] = src[i];                           // fully coalesced HBM read
    __syncthreads();
    int t = threadIdx.x;
    if (t >= TILE_A) return;                       // waves 2,3 load-only
    int gid = blk * TILE_A + t;
    int b = gid / N_ANC;                           // tiles may straddle images: per-anchor b
    int n = gid - b * N_ANC;
    const float* row = s + t * ROW_F;              // LDS stride 85: <=2 lanes/bank, free
    float obj = row[4];
    bool valid = (obj > CONF_T);                   // ~4.2% pass
    float best = -1.0f; int bj = 0;
    if (valid) {
        #pragma unroll 8
        for (int c = 0; c < NCLS; ++c) {
            float sc = __fmul_rn(row[5 + c], obj); // exact repl of cls*obj
            if (sc > best) { best = sc; bj = c; }  // strict > == first-max (matches argmax)
        }
        valid = (best > CONF_T);                   // rare dropout, must match reference
    }
    int lane = t & 63;
    u64 act = __ballot(valid);
    while (act) {                                  // <=2 iterations (<=2 images per wave)
        int leader = __ffsll((long long)act) - 1;
        int b0 = __shfl(b, leader);
        u64 grp = __ballot(valid && (b == b0));
        if (valid && (b == b0)) {
            int ofs = __popcll(grp & ((1ULL << lane) - 1ULL));
            int base = 0;
            if (lane == leader) base = atomicAdd(&count[b0 * 16], __popcll(grp));
            base = __shfl(base, leader);
            int pos = base + ofs;
            if (pos < CAND_CAP) {
                unsigned ord = __float_as_uint(best) ^ 0x80000000u;  // best>0 -> monotone
                u64 key = ((u64)ord << 22) | ((u64)(32767 - n) << 7) | (u64)bj;
                keys[b0 * CAND_CAP + pos] = key;
                kbox[b0 * CAND_CAP + pos] = make_float4(row[0], row[1], row[2], row[3]);
            }
        }
        act &= ~grp;
    }
}

// Kernel 2: O(M^2) rank-sort, 2 slice-blocks/image (ranks injective -> disjoint writes).
// rank(t) = #{j: key[j] > key[t]} reproduces top_k order exactly. M <= 2048 == K_NMS,
// so every rank lands. Inner loop 8-way batched for MLP (was a 120-cy/iter chain).
__global__ __launch_bounds__(1024) void rank_kernel(const u64* __restrict__ keys,
                                                    const int* __restrict__ count,
                                                    int* __restrict__ ncand,
                                                    const float4* __restrict__ kbox,
                                                    float4* __restrict__ boxes,
                                                    float* __restrict__ area,
                                                    int* __restrict__ candidx) {
    __shared__ u64 s_keys[CAND_CAP];               // 16 KB
    int b = blockIdx.x, sl = blockIdx.y;
    int M = min(count[b * 16], CAND_CAP);
    if (sl == 0 && threadIdx.x == 0) ncand[b] = M;
    int t0 = sl * 1024;
    if (t0 >= M) return;                           // block-uniform exit
    for (int t = threadIdx.x; t < M; t += 1024)
        s_keys[t] = keys[b * CAND_CAP + t];
    __syncthreads();
    int t = t0 + threadIdx.x;
    if (t >= M) return;
    u64 key = s_keys[t];
    int r0 = 0, r1 = 0, r2 = 0, r3 = 0;
    int j = 0;
    for (; j + 8 <= M; j += 8) {                   // 8 independent LDS broadcasts in flight
        u64 k0 = s_keys[j],     k1 = s_keys[j + 1];
        u64 k2 = s_keys[j + 2], k3 = s_keys[j + 3];
        u64 k4 = s_keys[j + 4], k5 = s_keys[j + 5];
        u64 k6 = s_keys[j + 6], k7 = s_keys[j + 7];
        r0 += (k0 > key) + (k4 > key);
        r1 += (k1 > key) + (k5 > key);
        r2 += (k2 > key) + (k6 > key);
        r3 += (k3 > key) + (k7 > key);
    }
    for (; j < M; ++j) r0 += (s_keys[j] > key) ? 1 : 0;
    int rank = (r0 + r1) + (r2 + r3);
    float4 b4 = kbox[b * CAND_CAP + t];            // coalesced by t
    int cls = (int)(key & 127ULL);
    int n = 32767 - (int)((key >> 7) & 32767ULL);
    float off = (float)cls * MAX_WH;                           // exact product
    float x1 = __fadd_rn(__fsub_rn(b4.x, __fmul_rn(b4.z, 0.5f)), off);
    float y1 = __fadd_rn(__fsub_rn(b4.y, __fmul_rn(b4.w, 0.5f)), off);
    float x2 = __fadd_rn(__fadd_rn(b4.x, __fmul_rn(b4.z, 0.5f)), off);
    float y2 = __fadd_rn(__fadd_rn(b4.y, __fmul_rn(b4.w, 0.5f)), off);
    size_t o = (size_t)b * K_NMS + rank;
    boxes[o] = make_float4(x1, y1, x2, y2);
    area[o] = __fmul_rn(__fsub_rn(x2, x1), __fsub_rn(y2, y1));  // from offset coords, like ref
    candidx[o] = n;
}

// Kernel 3: suppression bit-matrix. Row i, word w in [i>>6, ceil(M/64)): bit j =
// (iou(i,j)>0.45 && j>i). Words >= ceil(M/64) unwritten: masked by vmask in kernel 4.
__global__ __launch_bounds__(256) void iou_kernel(const float4* __restrict__ boxes,
                                                  const float* __restrict__ area,
                                                  const int* __restrict__ ncand,
                                                  u64* __restrict__ supmat) {
    __shared__ float4 s_box[K_NMS];                // 32 KB
    __shared__ float s_area[K_NMS];                // 8 KB
    int b = blockIdx.y;
    int M = ncand[b];
    int r0 = blockIdx.x * 32;
    if (r0 >= M) return;
    int wend = (M + 63) >> 6;                      // columns >= wend*64 are inert
    int stage = wend << 6;
    for (int t = threadIdx.x; t < stage; t += 256) {
        if (t < M) {
            s_box[t] = boxes[(size_t)b * K_NMS + t];
            s_area[t] = area[(size_t)b * K_NMS + t];
        } else {                                   // synthesized inert filler (never stored)
            s_box[t] = make_float4(0.f, 0.f, 0.f, 0.f);
            s_area[t] = 0.f;
        }
    }
    __syncthreads();
    int wave = threadIdx.x >> 6, lane = threadIdx.x & 63;
    for (int rr = 0; rr < 8; ++rr) {
        int i = r0 + wave * 8 + rr;                // wave-uniform
        if (i >= M) continue;
        float4 bi = s_box[i]; float ai = s_area[i];
        int wstart = i >> 6;
        u64* outrow = supmat + ((size_t)b * K_NMS + i) * 32;
        if (lane < wstart) outrow[lane] = 0ULL;    // low words read by kernel 4 accumulation
        for (int w = wstart; w < wend; ++w) {
            int j = w * 64 + lane;
            float4 bj = s_box[j]; float aj = s_area[j];
            float iw = fmaxf(__fsub_rn(fminf(bi.z, bj.z), fmaxf(bi.x, bj.x)), 0.0f);
            float ih = fmaxf(__fsub_rn(fminf(bi.w, bj.w), fmaxf(bi.y, bj.y)), 0.0f);
            float inter = __fmul_rn(iw, ih);
            float uni = __fsub_rn(__fadd_rn(ai, aj), inter);
            float iou = (uni > 0.0f) ? __fdiv_rn(inter, uni) : 0.0f;  // exact repl of ref
            bool bit = (j > i) && (iou > IOU_T);
            u64 mask = __ballot(bit);
            if (lane == 0) outrow[w] = mask;
        }
    }
}

// Kernel 4: sequential greedy suppression (1 wave/image, double-buffered staging)
// + rank<1000 + 80-wide sums with per-row coalesced reads.
__global__ __launch_bounds__(256) void nms_kernel(const u64* __restrict__ supmat,
                                                  const int* __restrict__ ncand,
                                                  const int* __restrict__ candidx,
                                                  const float* __restrict__ pred,
                                                  float* __restrict__ out) {
    __shared__ u64 s_rows[2][64 * 32];             // 2 x 16 KB double buffer
    __shared__ int s_klist[MAX_DET];
    __shared__ double s_part[2][NCLS];
    __shared__ int s_K;
    int b = blockIdx.x;
    int M = ncand[b];
    int tid = threadIdx.x;
    int lane = tid & 63, wave = tid >> 6;
    unsigned remv_lo = 0u, remv_hi = 0u;           // lane w (<32) holds u64 word w of removal mask
    const u64* base = supmat + (size_t)b * K_NMS * 32;
    int nchunks = (M + 63) >> 6;
    for (int t = tid; t < 2048 && nchunks > 0; t += 256)
        s_rows[0][t] = base[t];                    // prologue: stage chunk 0
    __syncthreads();
    for (int c = 0; c < nchunks; ++c) {
        int buf = c & 1;
        if (wave != 0) {                           // waves 1-3: prefetch chunk c+1
            int cn = c + 1;
            if (cn < nchunks) {
                size_t off = (size_t)cn * 2048;
                for (int t = tid - 64; t < 2048; t += 192)
                    s_rows[buf ^ 1][t] = base[off + t];
            }
        } else {                                   // wave 0: serial greedy scan of chunk c
            int c0 = c * 64;
            int lim = min(64, M - c0);
            for (int ii = 0; ii < lim; ++ii) {
                int i = c0 + ii;
                unsigned half = ((i >> 5) & 1) ? remv_hi : remv_lo;
                unsigned wv = __builtin_amdgcn_readlane(half, i >> 6);
                bool kept = ((wv >> (i & 31)) & 1u) == 0u;   // uniform across wave
                u64 rowm = (lane < 32) ? s_rows[buf][ii * 32 + lane] : 0ULL;
                if (kept) {
                    remv_lo |= (unsigned)rowm;
                    remv_hi |= (unsigned)(rowm >> 32);
                }
            }
        }
        __syncthreads();
    }
    if (wave == 0) {
        int w = lane;
        u64 keepw = 0ULL;
        if (w < 32) {
            int lo = w * 64;
            u64 vmask = (M >= lo + 64) ? ~0ULL : (M <= lo ? 0ULL : ((1ULL << (M - lo)) - 1ULL));
            u64 remv = ((u64)remv_hi << 32) | remv_lo;
            keepw = (~remv) & vmask;               // vmask kills garbage words >= ceil(M/64)
        }
        int c = __popcll(keepw);
        int sc = c;
        for (int o = 1; o < 64; o <<= 1) { int v = __shfl_up(sc, o); if (lane >= o) sc += v; }
        int excl = sc - c;
        int Ktot = __shfl(sc, 63);
        int K = min(Ktot, MAX_DET);
        if (lane == 0) s_K = K;
        u64 m = keepw; int r = excl;
        while (m) {
            int bit = __ffsll(m) - 1; m &= m - 1;
            if (r < K) s_klist[r] = candidx[(size_t)b * K_NMS + w * 64 + bit];
            r++;
        }
    }
    __syncthreads();
    int K = s_K;
    // 3 groups of 80 CONSECUTIVE threads; group reads ONE row segment (320 B,
    // 5-6 lines) per iteration; unroll 8 -> 8 independent load chains.
    int g = tid / NCLS;                            // 0,1,2 active; tid>=240 idle
    int c = tid - g * NCLS;
    double acc = 0.0;
    if (g < 3) {
        #pragma unroll 8
        for (int k = g; k < K; k += 3) {
            int n = s_klist[k];
            const float* row = pred + ((size_t)b * N_ANC + n) * ROW_F;
            acc += (double)__fmul_rn(row[5 + c], row[4]);
        }
        if (g > 0) s_part[g - 1][c] = acc;
    }
    __syncthreads();
    if (tid < NCLS)
        out[b * NCLS + tid] = (float)(acc + s_part[0][tid] + s_part[1][tid]);
}

extern "C" void kernel_launch(void* const* d_in, const int* in_sizes, int n_in,
                              void* d_out, int out_size, void* d_ws, size_t ws_size,
                              hipStream_t stream) {
    const float* pred = (const float*)d_in[0];
    float* out = (float*)d_out;
    char* w = (char*)d_ws;
    int* count    = (int*)(w + OFF_COUNT);         // padded: count[b*16]
    int* ncand    = (int*)(w + OFF_NCAND);
    u64* keys     = (u64*)(w + OFF_KEYS);
    float4* kbox  = (float4*)(w + OFF_KBOX);
    float4* boxes = (float4*)(w + OFF_BOXES);
    float* area   = (float*)(w + OFF_AREA);
    int* candidx  = (int*)(w + OFF_CIDX);
    u64* supmat   = (u64*)(w + OFF_SUP);

    hipMemsetAsync(w, 0, 4096, stream);            // count (padded) + ncand
    scan_kernel<<<(B_IMG * N_ANC) / TILE_A, 256, 0, stream>>>(pred, count, keys, kbox);
    rank_kernel<<<dim3(B_IMG, RANK_SLICES), 1024, 0, stream>>>(keys, count, ncand, kbox, boxes, area, candidx);
    iou_kernel<<<dim3(64, B_IMG), 256, 0, stream>>>(boxes, area, ncand, supmat);
    nms_kernel<<<B_IMG, 256, 0, stream>>>(supmat, ncand, candidx, pred, out);
}

// Round 11
// 377.961 us; speedup vs baseline: 2.1679x; 1.0348x over previous
//
#include <hip/hip_runtime.h>

typedef unsigned long long u64;

#define B_IMG 16
#define N_ANC 25200
#define NCLS 80
#define ROW_F 85           // 5 + 80 floats per anchor
#define CONF_T 0.25f
#define IOU_T 0.45f
#define MAX_DET 1000
#define K_NMS 2048
#define MAX_WH 7680.0f
#define CAND_CAP 2048      // per-image cap (mean ~1065 valid, sigma ~32 -> +30 sigma)
#define TILE_A 64          // anchors per scan tile (21.25 KB LDS -> 7 blocks/CU)
#define TILE_F (TILE_A * ROW_F)
#define RANK_SLICES 2

// ---------------- workspace layout (bytes, total ~9.97 MB) ----------------
#define OFF_COUNT 0            // int count[16*16]  (64-B stride per image: no line sharing)
#define OFF_NCAND 1024         // int ncand[16]
#define OFF_KEYS  4096         // u64 keys[16][2048]      (256 KB)
#define OFF_KBOX  266240       // float4 kbox[16][2048]   (512 KB)
#define OFF_BOXES 790528       // float4 boxes[16][2048]  (512 KB)
#define OFF_AREA  1314816      // float area[16][2048]    (128 KB)
#define OFF_CIDX  1445888      // int candidx[16][2048]   (128 KB)
#define OFF_SUP   1576960      // u64 supmat[16][2048][32] (8 MB)

// Kernel 1: fused coalesced scan. Stages 64 full rows (21.25 KB) into LDS via
// float4 loads, one thread per anchor gates + class-maxes FROM LDS.
// Compaction via wave-aggregated atomics on 64B-padded counters (R7 lesson:
// per-thread same-line atomics serialize at ~12ns each).
__global__ __launch_bounds__(256) void scan_kernel(const float* __restrict__ pred,
                                                   int* __restrict__ count,
                                                   u64* __restrict__ keys,
                                                   float4* __restrict__ kbox) {
    __shared__ float s[TILE_F];
    int blk = blockIdx.x;                          // 6300 tiles, exact cover
    const float4* src = (const float4*)(pred + (size_t)blk * TILE_F);
    float4* dst = (float4*)s;
    for (int i = threadIdx.x; i < TILE_F / 4; i += 256)
        dst[i] = src[i];                           // fully coalesced HBM read
    __syncthreads();
    int t = threadIdx.x;
    if (t >= TILE_A) return;                       // waves 1-3 load-only
    int gid = blk * TILE_A + t;
    int b = gid / N_ANC;                           // tiles may straddle images
    int n = gid - b * N_ANC;
    const float* row = s + t * ROW_F;              // LDS stride 85: <=2 lanes/bank, free
    float obj = row[4];
    bool valid = (obj > CONF_T);                   // ~4.2% pass
    float best = -1.0f; int bj = 0;
    if (valid) {
        #pragma unroll 8
        for (int c = 0; c < NCLS; ++c) {
            float sc = __fmul_rn(row[5 + c], obj); // exact repl of cls*obj
            if (sc > best) { best = sc; bj = c; }  // strict > == first-max (matches argmax)
        }
        valid = (best > CONF_T);                   // rare dropout, must match reference
    }
    int lane = t & 63;
    u64 act = __ballot(valid);
    while (act) {                                  // <=2 iterations (<=2 images per wave)
        int leader = __ffsll((long long)act) - 1;
        int b0 = __shfl(b, leader);
        u64 grp = __ballot(valid && (b == b0));
        if (valid && (b == b0)) {
            int ofs = __popcll(grp & ((1ULL << lane) - 1ULL));
            int base = 0;
            if (lane == leader) base = atomicAdd(&count[b0 * 16], __popcll(grp));
            base = __shfl(base, leader);
            int pos = base + ofs;
            if (pos < CAND_CAP) {
                unsigned ord = __float_as_uint(best) ^ 0x80000000u;  // best>0 -> monotone
                u64 key = ((u64)ord << 22) | ((u64)(32767 - n) << 7) | (u64)bj;
                keys[b0 * CAND_CAP + pos] = key;
                kbox[b0 * CAND_CAP + pos] = make_float4(row[0], row[1], row[2], row[3]);
            }
        }
        act &= ~grp;
    }
}

// Kernel 2: O(M^2) rank-sort, 2 slice-blocks/image (ranks injective -> disjoint writes).
// rank(t) = #{j: key[j] > key[t]} reproduces top_k order exactly; 8-way batched for MLP.
__global__ __launch_bounds__(1024) void rank_kernel(const u64* __restrict__ keys,
                                                    const int* __restrict__ count,
                                                    int* __restrict__ ncand,
                                                    const float4* __restrict__ kbox,
                                                    float4* __restrict__ boxes,
                                                    float* __restrict__ area,
                                                    int* __restrict__ candidx) {
    __shared__ u64 s_keys[CAND_CAP];               // 16 KB
    int b = blockIdx.x, sl = blockIdx.y;
    int M = min(count[b * 16], CAND_CAP);
    if (sl == 0 && threadIdx.x == 0) ncand[b] = M;
    int t0 = sl * 1024;
    if (t0 >= M) return;                           // block-uniform exit
    for (int t = threadIdx.x; t < M; t += 1024)
        s_keys[t] = keys[b * CAND_CAP + t];
    __syncthreads();
    int t = t0 + threadIdx.x;
    if (t >= M) return;
    u64 key = s_keys[t];
    int r0 = 0, r1 = 0, r2 = 0, r3 = 0;
    int j = 0;
    for (; j + 8 <= M; j += 8) {                   // 8 independent LDS broadcasts in flight
        u64 k0 = s_keys[j],     k1 = s_keys[j + 1];
        u64 k2 = s_keys[j + 2], k3 = s_keys[j + 3];
        u64 k4 = s_keys[j + 4], k5 = s_keys[j + 5];
        u64 k6 = s_keys[j + 6], k7 = s_keys[j + 7];
        r0 += (k0 > key) + (k4 > key);
        r1 += (k1 > key) + (k5 > key);
        r2 += (k2 > key) + (k6 > key);
        r3 += (k3 > key) + (k7 > key);
    }
    for (; j < M; ++j) r0 += (s_keys[j] > key) ? 1 : 0;
    int rank = (r0 + r1) + (r2 + r3);
    float4 b4 = kbox[b * CAND_CAP + t];            // coalesced by t
    int cls = (int)(key & 127ULL);
    int n = 32767 - (int)((key >> 7) & 32767ULL);
    float off = (float)cls * MAX_WH;                           // exact product
    float x1 = __fadd_rn(__fsub_rn(b4.x, __fmul_rn(b4.z, 0.5f)), off);
    float y1 = __fadd_rn(__fsub_rn(b4.y, __fmul_rn(b4.w, 0.5f)), off);
    float x2 = __fadd_rn(__fadd_rn(b4.x, __fmul_rn(b4.z, 0.5f)), off);
    float y2 = __fadd_rn(__fadd_rn(b4.y, __fmul_rn(b4.w, 0.5f)), off);
    size_t o = (size_t)b * K_NMS + rank;
    boxes[o] = make_float4(x1, y1, x2, y2);
    area[o] = __fmul_rn(__fsub_rn(x2, x1), __fsub_rn(y2, y1));  // from offset coords, like ref
    candidx[o] = n;
}

// Kernel 3: suppression bit-matrix. Row i, word w in [i>>6, ceil(M/64)): bit j =
// (iou(i,j)>0.45 && j>i). Words >= ceil(M/64) unwritten: masked by vmask in kernel 4.
__global__ __launch_bounds__(256) void iou_kernel(const float4* __restrict__ boxes,
                                                  const float* __restrict__ area,
                                                  const int* __restrict__ ncand,
                                                  u64* __restrict__ supmat) {
    __shared__ float4 s_box[K_NMS];                // 32 KB
    __shared__ float s_area[K_NMS];                // 8 KB
    int b = blockIdx.y;
    int M = ncand[b];
    int r0 = blockIdx.x * 32;
    if (r0 >= M) return;
    int wend = (M + 63) >> 6;                      // columns >= wend*64 are inert
    int stage = wend << 6;
    for (int t = threadIdx.x; t < stage; t += 256) {
        if (t < M) {
            s_box[t] = boxes[(size_t)b * K_NMS + t];
            s_area[t] = area[(size_t)b * K_NMS + t];
        } else {                                   // synthesized inert filler (never stored)
            s_box[t] = make_float4(0.f, 0.f, 0.f, 0.f);
            s_area[t] = 0.f;
        }
    }
    __syncthreads();
    int wave = threadIdx.x >> 6, lane = threadIdx.x & 63;
    for (int rr = 0; rr < 8; ++rr) {
        int i = r0 + wave * 8 + rr;                // wave-uniform
        if (i >= M) continue;
        float4 bi = s_box[i]; float ai = s_area[i];
        int wstart = i >> 6;
        u64* outrow = supmat + ((size_t)b * K_NMS + i) * 32;
        if (lane < wstart) outrow[lane] = 0ULL;    // low words read by kernel 4 register scan
        for (int w = wstart; w < wend; ++w) {
            int j = w * 64 + lane;
            float4 bj = s_box[j]; float aj = s_area[j];
            float iw = fmaxf(__fsub_rn(fminf(bi.z, bj.z), fmaxf(bi.x, bj.x)), 0.0f);
            float ih = fmaxf(__fsub_rn(fminf(bi.w, bj.w), fmaxf(bi.y, bj.y)), 0.0f);
            float inter = __fmul_rn(iw, ih);
            float uni = __fsub_rn(__fadd_rn(ai, aj), inter);
            float iou = (uni > 0.0f) ? __fdiv_rn(inter, uni) : 0.0f;  // exact repl of ref
            bool bit = (j > i) && (iou > IOU_T);
            u64 mask = __ballot(bit);
            if (lane == 0) outrow[w] = mask;
        }
    }
}

// Kernel 4: sequential greedy suppression + rank<1000 + 80-wide sums.
// Serial scan restructured (R8 post-mortem: 260 cy/iter from on-chain ds_read +
// VALU->readlane round trips): chunks are 64-aligned so the kept-bit word is
// wave-uniform per chunk -> keep it as scalar s_cur (SALU chain ~10 cy/iter);
// the chunk's 64 rows are pre-loaded into registers (independent ds_reads).
__global__ __launch_bounds__(256) void nms_kernel(const u64* __restrict__ supmat,
                                                  const int* __restrict__ ncand,
                                                  const int* __restrict__ candidx,
                                                  const float* __restrict__ pred,
                                                  float* __restrict__ out) {
    __shared__ u64 s_rows[2][64 * 32];             // 2 x 16 KB double buffer
    __shared__ int s_klist[MAX_DET];
    __shared__ double s_part[2][NCLS];
    __shared__ int s_K;
    int b = blockIdx.x;
    int M = ncand[b];
    int tid = threadIdx.x;
    int lane = tid & 63, wave = tid >> 6;
    unsigned remv_lo = 0u, remv_hi = 0u;           // lane w (<32) holds u64 word w of removal mask
    const u64* base = supmat + (size_t)b * K_NMS * 32;
    int nchunks = (M + 63) >> 6;                   // <= 32, so readlane source lane < 32
    for (int t = tid; t < 2048 && nchunks > 0; t += 256)
        s_rows[0][t] = base[t];                    // prologue: stage chunk 0
    __syncthreads();
    for (int c = 0; c < nchunks; ++c) {
        int buf = c & 1;
        if (wave != 0) {                           // waves 1-3: prefetch chunk c+1
            int cn = c + 1;
            if (cn < nchunks) {
                size_t off = (size_t)cn * 2048;
                for (int t = tid - 64; t < 2048; t += 192)
                    s_rows[buf ^ 1][t] = base[off + t];
            }
        } else {                                   // wave 0: scan chunk c
            int c0 = c * 64;
            int lim = min(64, M - c0);
            // s_cur = removal word c (the word every kept-test in this chunk reads)
            unsigned cl = __builtin_amdgcn_readlane(remv_lo, c);
            unsigned ch = __builtin_amdgcn_readlane(remv_hi, c);
            u64 s_cur = ((u64)ch << 32) | cl;
            // pre-load all 64 rows' word-lane into registers: independent ds_reads
            u64 rm[64];
            #pragma unroll
            for (int z = 0; z < 64; ++z)
                rm[z] = (lane < 32) ? s_rows[buf][z * 32 + lane] : 0ULL;
            #pragma unroll
            for (int z = 0; z < 64; ++z) {
                if (z < lim) {                     // uniform guard
                    unsigned wlo = __builtin_amdgcn_readlane((unsigned)rm[z], c);
                    unsigned whi = __builtin_amdgcn_readlane((unsigned)(rm[z] >> 32), c);
                    u64 wrd = ((u64)whi << 32) | wlo;          // row z's word c (off-chain)
                    bool kept = ((s_cur >> z) & 1ULL) == 0ULL; // bit z of word c
                    u64 msk = kept ? ~0ULL : 0ULL;
                    s_cur |= wrd & msk;                        // SALU critical chain
                    remv_lo |= (unsigned)rm[z] & (unsigned)msk;
                    remv_hi |= (unsigned)(rm[z] >> 32) & (unsigned)msk;
                }
            }
        }
        __syncthreads();
    }
    if (wave == 0) {
        int w = lane;
        u64 keepw = 0ULL;
        if (w < 32) {
            int lo = w * 64;
            u64 vmask = (M >= lo + 64) ? ~0ULL : (M <= lo ? 0ULL : ((1ULL << (M - lo)) - 1ULL));
            u64 remv = ((u64)remv_hi << 32) | remv_lo;
            keepw = (~remv) & vmask;               // vmask kills garbage words >= ceil(M/64)
        }
        int c = __popcll(keepw);
        int sc = c;
        for (int o = 1; o < 64; o <<= 1) { int v = __shfl_up(sc, o); if (lane >= o) sc += v; }
        int excl = sc - c;
        int Ktot = __shfl(sc, 63);
        int K = min(Ktot, MAX_DET);
        if (lane == 0) s_K = K;
        u64 m = keepw; int r = excl;
        while (m) {
            int bit = __ffsll(m) - 1; m &= m - 1;
            if (r < K) s_klist[r] = candidx[(size_t)b * K_NMS + w * 64 + bit];
            r++;
        }
    }
    __syncthreads();
    int K = s_K;
    // 3 groups of 80 CONSECUTIVE threads; group reads ONE row segment (320 B,
    // 5-6 lines) per iteration; unroll 8 -> 8 independent load chains.
    int g = tid / NCLS;                            // 0,1,2 active; tid>=240 idle
    int c = tid - g * NCLS;
    double acc = 0.0;
    if (g < 3) {
        #pragma unroll 8
        for (int k = g; k < K; k += 3) {
            int n = s_klist[k];
            const float* row = pred + ((size_t)b * N_ANC + n) * ROW_F;
            acc += (double)__fmul_rn(row[5 + c], row[4]);
        }
        if (g > 0) s_part[g - 1][c] = acc;
    }
    __syncthreads();
    if (tid < NCLS)
        out[b * NCLS + tid] = (float)(acc + s_part[0][tid] + s_part[1][tid]);
}

extern "C" void kernel_launch(void* const* d_in, const int* in_sizes, int n_in,
                              void* d_out, int out_size, void* d_ws, size_t ws_size,
                              hipStream_t stream) {
    const float* pred = (const float*)d_in[0];
    float* out = (float*)d_out;
    char* w = (char*)d_ws;
    int* count    = (int*)(w + OFF_COUNT);         // padded: count[b*16]
    int* ncand    = (int*)(w + OFF_NCAND);
    u64* keys     = (u64*)(w + OFF_KEYS);
    float4* kbox  = (float4*)(w + OFF_KBOX);
    float4* boxes = (float4*)(w + OFF_BOXES);
    float* area   = (float*)(w + OFF_AREA);
    int* candidx  = (int*)(w + OFF_CIDX);
    u64* supmat   = (u64*)(w + OFF_SUP);

    hipMemsetAsync(w, 0, 4096, stream);            // count (padded) + ncand
    scan_kernel<<<(B_IMG * N_ANC) / TILE_A, 256, 0, stream>>>(pred, count, keys, kbox);
    rank_kernel<<<dim3(B_IMG, RANK_SLICES), 1024, 0, stream>>>(keys, count, ncand, kbox, boxes, area, candidx);
    iou_kernel<<<dim3(64, B_IMG), 256, 0, stream>>>(boxes, area, ncand, supmat);
    nms_kernel<<<B_IMG, 256, 0, stream>>>(supmat, ncand, candidx, pred, out);
}